// Round 7
// baseline (3979.841 us; speedup 1.0000x reference)
//
#include <hip/hip_runtime.h>
#include <hip/hip_bf16.h>
#include <stdint.h>

#define Bb 32
#define Tt 512
#define Dd 1024
#define Hh 1024
#define Cc 1000
#define Mm (Bb*Tt)

typedef float f32x4 __attribute__((ext_vector_type(4)));
typedef short bf16x8 __attribute__((ext_vector_type(8)));
typedef int   i32x4  __attribute__((ext_vector_type(4)));

#define MFMA16(a,b,c) __builtin_amdgcn_mfma_f32_16x16x32_bf16(a,b,c,0,0,0)

static __device__ __forceinline__ unsigned short f2b(float f){
  __hip_bfloat16 h = __float2bfloat16(f);
  union { __hip_bfloat16 h; unsigned short u; } cv; cv.h = h; return cv.u;
}
static __device__ __forceinline__ float b2f(unsigned short u){
  union { unsigned int i; float f; } cv; cv.i = ((unsigned int)u) << 16; return cv.f;
}

static __device__ __forceinline__ void async16(const ushort* g, ushort* l){
  __builtin_amdgcn_global_load_lds((const __attribute__((address_space(1))) unsigned int*)g,
                                   (__attribute__((address_space(3))) unsigned int*)l,
                                   16, 0, 0);
}

// FAST (same-XCD): agent scope = sc1 (bypass L1, coherent at XCD L2).
// safe (cross-XCD): system scope = sc0 sc1 (coherent at L3). R4/R6-proven.
template<int FAST>
static __device__ __forceinline__ bf16x8 h_load(const ushort* p){
  bf16x8 r;
  if constexpr (FAST)
    asm volatile("global_load_dwordx4 %0, %1, off sc1" : "=v"(r) : "v"(p) : "memory");
  else
    asm volatile("global_load_dwordx4 %0, %1, off sc0 sc1" : "=v"(r) : "v"(p) : "memory");
  return r;
}
template<int FAST>
static __device__ __forceinline__ void h_store(ushort* p, unsigned int v){
  if constexpr (FAST)
    asm volatile("global_store_dword %0, %1, off sc1" :: "v"(p), "v"(v) : "memory");
  else
    asm volatile("global_store_dword %0, %1, off sc0 sc1" :: "v"(p), "v"(v) : "memory");
}
template<int FAST>
static __device__ __forceinline__ i32x4 flag_load4(const int* p){
  i32x4 r;
  if constexpr (FAST)
    asm volatile("global_load_dwordx4 %0, %1, off sc1" : "=v"(r) : "v"(p) : "memory");
  else
    asm volatile("global_load_dwordx4 %0, %1, off sc0 sc1" : "=v"(r) : "v"(p) : "memory");
  return r;
}
template<int FAST>
static __device__ __forceinline__ void flag_store(int* p, int v){
  if constexpr (FAST)
    asm volatile("global_store_dword %0, %1, off sc1" :: "v"(p), "v"(v) : "memory");
  else
    asm volatile("global_store_dword %0, %1, off sc0 sc1" :: "v"(p), "v"(v) : "memory");
}

static __device__ __forceinline__ int load4sys(const int* p){
  int v;
  asm volatile("global_load_dword %0, %1, off sc0 sc1" : "=v"(v) : "v"(p) : "memory");
  asm volatile("s_waitcnt vmcnt(0)" ::: "memory");
  return v;
}
static __device__ __forceinline__ void store4sys(int* p, int v){
  asm volatile("global_store_dword %0, %1, off sc0 sc1" :: "v"(p), "v"(v) : "memory");
}

// ---------------- conversion kernels ----------------

__global__ void cvt_bf16(const float* __restrict__ in, ushort* __restrict__ out, int n4){
  int i = blockIdx.x*256 + threadIdx.x;
  if (i < n4){
    const float4 v = ((const float4*)in)[i];
    ushort4 o;
    o.x = f2b(v.x); o.y = f2b(v.y); o.z = f2b(v.z); o.w = f2b(v.w);
    ((ushort4*)out)[i] = o;
  }
}

__global__ void pad_w2(const float* __restrict__ w2, const float* __restrict__ b2,
                       ushort* __restrict__ w2p, float* __restrict__ b2p){
  int i = blockIdx.x*256 + threadIdx.x;
  int r = i >> 10, c = i & 1023;
  w2p[i] = (r < Cc) ? f2b(w2[r*1024 + c]) : (ushort)0;
  if (i < 1024) b2p[i] = (i < Cc) ? b2[i] : 0.f;
}

// ---------------- generic bf16 MFMA GEMM (m97 structure) ----------------
// PERM_A / PERM_C: buffer stored row-permuted [(m&511)*32 + (m>>9)] = [t*32+b]

template<int RELU, int OUT_BF16, int PERM_A, int PERM_C>
__global__ __launch_bounds__(256) void gemm_bt(
    const ushort* __restrict__ A, const ushort* __restrict__ Bm,
    const float* __restrict__ bias, void* __restrict__ Cp,
    int M, int N, int K, int ldc, int nout)
{
  __shared__ ushort As[128*32];
  __shared__ ushort Bs[128*32];
  const int tid  = threadIdx.x;
  const int lane = tid & 63;
  const int wave = tid >> 6;
  const int wr = wave >> 1, wc = wave & 1;
  const int r0 = lane & 15, kg = lane >> 4;
  const int m0 = blockIdx.x*128, n0 = blockIdx.y*128;

  const int lrA0 = m0 + (tid>>2);
  const int lrA1 = lrA0 + 64;
  const size_t prA0 = PERM_A ? (size_t)((lrA0 & 511)*32 + (lrA0 >> 9)) : (size_t)lrA0;
  const size_t prA1 = PERM_A ? (size_t)((lrA1 & 511)*32 + (lrA1 >> 9)) : (size_t)lrA1;
  const ushort* aG0 = A  + prA0*K + (tid&3)*8;
  const ushort* aG1 = A  + prA1*K + (tid&3)*8;
  const ushort* bG  = Bm + (size_t)(n0 + (tid>>2))*K + (tid&3)*8;
  ushort* aL = As + tid*8;
  ushort* bL = Bs + tid*8;
  const size_t rstep = (size_t)64*K;

  f32x4 acc[4][4] = {};

  for (int kt = 0; kt < K; kt += 32){
    __syncthreads();
    async16(aG0 + kt, aL);
    async16(aG1 + kt, aL + 2048);
    async16(bG + kt,         bL);
    async16(bG + kt + rstep, bL + 2048);
    __syncthreads();
    bf16x8 af[4], bf_[4];
#pragma unroll
    for (int i=0;i<4;i++) af[i]  = *(const bf16x8*)&As[(wr*64 + i*16 + r0)*32 + kg*8];
#pragma unroll
    for (int j=0;j<4;j++) bf_[j] = *(const bf16x8*)&Bs[(wc*64 + j*16 + r0)*32 + kg*8];
#pragma unroll
    for (int i=0;i<4;i++)
#pragma unroll
      for (int j=0;j<4;j++)
        acc[i][j] = MFMA16(af[i], bf_[j], acc[i][j]);
  }

  const int rowb = m0 + wr*64 + kg*4;
  const int colb = n0 + wc*64 + r0;
#pragma unroll
  for (int i=0;i<4;i++){
#pragma unroll
    for (int j=0;j<4;j++){
      const int c = colb + j*16;
      if (c >= nout) continue;
      const float bv = bias ? bias[c] : 0.f;
#pragma unroll
      for (int q=0;q<4;q++){
        const int r = rowb + i*16 + q;
        const size_t pr = PERM_C ? (size_t)((r & 511)*32 + (r >> 9)) : (size_t)r;
        float v = acc[i][j][q] + bv;
        if (RELU) v = fmaxf(v, 0.f);
        if (OUT_BF16) ((ushort*)Cp)[pr*ldc + c] = f2b(v);
        else          ((float* )Cp)[pr*ldc + c] = v;
      }
    }
  }
}

// ---------------- persistent GRU scan: flag-published, per-XCD groups ----------------
// 256 WGs of 512 thr. Group g = {bid : bid%8==g} (32 members) owns batches
// [4g,4g+4); member m owns hidden units [32m,32m+32). Member publishes its
// 64 h-dwords then (after vmcnt drain) flag[g*32+m]=t+1. Readers poll one
// 16B flag vector, then load data once.

template<int FAST>
static __device__ __forceinline__ void scan_body(
    const int g, const int m, const int tid,
    const ushort* __restrict__ Whh, const float* __restrict__ bhh,
    const ushort* __restrict__ gxT, ushort* __restrict__ hsAll,
    int* __restrict__ flags, float* __restrict__ red)
{
  const int wave = tid >> 6;          // K-slice [wave*128, +128)
  const int lane = tid & 63;
  const int r0 = lane & 15, kg = lane >> 4;
  const int kbase = wave*128 + kg*8;

  // weight-stationary: 24 bf16x8 frags, volatile-asm loads (non-rematerializable)
  bf16x8 wb[6][4];
#pragma unroll
  for (int n=0;n<6;n++){
    const ushort* wr_ = Whh + ((size_t)((n>>1)*1024 + m*32 + (n&1)*16 + r0))*1024 + kbase;
#pragma unroll
    for (int ks=0;ks<4;ks++)
      asm volatile("global_load_dwordx4 %0, %1, off" : "=v"(wb[n][ks]) : "v"(wr_ + ks*32));
  }
  asm volatile("s_waitcnt vmcnt(0)" ::: "memory");

  // epilogue role (wave0): batch eb, unit pair (u0, u0+1)
  const int eb = tid >> 4;
  const int u0 = (tid & 15)*2;
  const int jg = m*32 + u0;
  float br0=0,br1=0,bz0=0,bz1=0,bn0=0,bn1=0;
  if (tid < 64){
    br0 = bhh[jg];       br1 = bhh[jg+1];
    bz0 = bhh[1024+jg];  bz1 = bhh[1024+jg+1];
    bn0 = bhh[2048+jg];  bn1 = bhh[2048+jg+1];
  }
  float hold0 = 0.f, hold1 = 0.f;

  // gx register double-buffer (wave0 only)
  unsigned xr=0, xz=0, xn=0, xrN=0, xzN=0, xnN=0;
  if (tid < 64){
    const ushort* gb = gxT + (size_t)(g*4 + eb)*3072 + jg;
    asm volatile("global_load_dword %0, %1, off" : "=v"(xr) : "v"(gb));
    asm volatile("global_load_dword %0, %1, off" : "=v"(xz) : "v"(gb + 1024));
    asm volatile("global_load_dword %0, %1, off" : "=v"(xn) : "v"(gb + 2048));
  }

  int* myflag = &flags[g*32 + m];
  const int* fl = &flags[g*32 + wave*4];   // the 4 members feeding my K-slice

  for (int t = 0; t < Tt; ++t){
    const int buf = t & 1;

    // ---- poll flags >= t (lane-uniform 16B load)
    for (;;){
      i32x4 f = flag_load4<FAST>(fl);
      asm volatile("s_waitcnt vmcnt(0)" ::: "memory");
      if (f[0] >= t && f[1] >= t && f[2] >= t && f[3] >= t) break;
    }

    // ---- h data loads (once; visible per flag ordering)
    const ushort* aB = hsAll + (size_t)(t*32 + g*4 + (r0 & 3))*1024 + kbase;
    bf16x8 ha[4];
#pragma unroll
    for (int ks=0;ks<4;ks++) ha[ks] = h_load<FAST>(aB + ks*32);

    // ---- gx(t+1) prefetch issued AFTER h loads (FIFO: vmcnt(3) waits h only)
    if (tid < 64){
      const int tn = (t+1 < Tt) ? t+1 : t;
      const ushort* gb = gxT + (size_t)(tn*32 + g*4 + eb)*3072 + jg;
      asm volatile("global_load_dword %0, %1, off" : "=v"(xrN) : "v"(gb));
      asm volatile("global_load_dword %0, %1, off" : "=v"(xzN) : "v"(gb + 1024));
      asm volatile("global_load_dword %0, %1, off" : "=v"(xnN) : "v"(gb + 2048));
      asm volatile("s_waitcnt vmcnt(3)" ::: "memory");
    } else {
      asm volatile("s_waitcnt vmcnt(0)" ::: "memory");
    }
    __builtin_amdgcn_sched_barrier(0);

    f32x4 acc[6] = {};
#pragma unroll
    for (int ks=0;ks<4;ks++)
#pragma unroll
      for (int n=0;n<6;n++)
        acc[n] = MFMA16(ha[ks], wb[n][ks], acc[n]);

#pragma unroll
    for (int n=0;n<6;n++)
      *(f32x4*)&red[buf*12288 + (wave*6 + n)*256 + lane*4] = acc[n];
    __syncthreads();   // single barrier per step (red double-buffered)

    if (tid < 64){
      float rs0=0,zs0=0,ns0=0, rs1=0,zs1=0,ns1=0;
      const float* rb = red + buf*12288;
#pragma unroll
      for (int w=0;w<8;w++){
        int j;
        j = u0;      rs0 += rb[(w*6 + (j>>4))*256 + (j&15)*4 + eb];
        j = u0+1;    rs1 += rb[(w*6 + (j>>4))*256 + (j&15)*4 + eb];
        j = 32+u0;   zs0 += rb[(w*6 + (j>>4))*256 + (j&15)*4 + eb];
        j = 33+u0;   zs1 += rb[(w*6 + (j>>4))*256 + (j&15)*4 + eb];
        j = 64+u0;   ns0 += rb[(w*6 + (j>>4))*256 + (j&15)*4 + eb];
        j = 65+u0;   ns1 += rb[(w*6 + (j>>4))*256 + (j&15)*4 + eb];
      }
      float h0, h1;
      {
        const float r = 1.f/(1.f + __expf(-(b2f((ushort)(xr & 0xffff)) + rs0 + br0)));
        const float z = 1.f/(1.f + __expf(-(b2f((ushort)(xz & 0xffff)) + zs0 + bz0)));
        const float a = b2f((ushort)(xn & 0xffff)) + r*(ns0 + bn0);
        const float e = __expf(-2.f*a);
        const float n = (1.f - e)/(1.f + e);
        h0 = (1.f - z)*n + z*hold0; hold0 = h0;
      }
      {
        const float r = 1.f/(1.f + __expf(-(b2f((ushort)(xr >> 16)) + rs1 + br1)));
        const float z = 1.f/(1.f + __expf(-(b2f((ushort)(xz >> 16)) + zs1 + bz1)));
        const float a = b2f((ushort)(xn >> 16)) + r*(ns1 + bn1);
        const float e = __expf(-2.f*a);
        const float n = (1.f - e)/(1.f + e);
        h1 = (1.f - z)*n + z*hold1; hold1 = h1;
      }
      const unsigned packed = (unsigned)f2b(h0) | ((unsigned)f2b(h1) << 16);
      h_store<FAST>(hsAll + (size_t)((t+1)*32 + g*4 + eb)*1024 + jg, packed);
      asm volatile("s_waitcnt vmcnt(0)" ::: "memory");   // drain h stores (wave FIFO)
      if (tid == 0) flag_store<FAST>(myflag, t+1);       // publish
    }
    xr = xrN; xz = xzN; xn = xnN;
  }
}

__global__ __launch_bounds__(512, 1) void gru_scan(
    const ushort* __restrict__ Whh, const float* __restrict__ bhh,
    const ushort* __restrict__ gxT,   // [t][b][3H]
    ushort* __restrict__ hsAll,       // [Tt+1][32][1024]; rows 0..31 zeroed
    int* __restrict__ flags,          // [8][32] step stamps, init 0
    int* __restrict__ xccTab)         // [0..255]=XCC publish, [256..263]=decision; init -1
{
  __shared__ float red[2*12288];
  __shared__ int fastFlag;
  const int bid = blockIdx.x;
  const int g = bid & 7, m = bid >> 3;
  const int tid = threadIdx.x;
  int* decTab = xccTab + 256;

  // mode agreement (R6-proven): publish XCC_ID; member 0 decides; bounded spin
  if (tid == 0){
    int myxcc;
    asm volatile("s_getreg_b32 %0, hwreg(HW_REG_XCC_ID)" : "=s"(myxcc));
    store4sys(&xccTab[bid], myxcc);
    if (m == 0){
      int ok = 1;
      long budget = 200000;
      for (int p = 0; p < 32 && ok; ++p){
        int v;
        do {
          v = load4sys(&xccTab[p*8 + g]);
          if (v == -1){ __builtin_amdgcn_s_sleep(1); if (--budget <= 0){ ok = 0; break; } }
        } while (v == -1);
        if (v != myxcc) ok = 0;
      }
      store4sys(&decTab[g], ok);
      fastFlag = ok;
    } else {
      int v;
      do {
        v = load4sys(&decTab[g]);
        if (v == -1) __builtin_amdgcn_s_sleep(1);
      } while (v == -1);
      fastFlag = v;
    }
  }
  __syncthreads();

  if (fastFlag) scan_body<1>(g, m, tid, Whh, bhh, gxT, hsAll, flags, red);
  else          scan_body<0>(g, m, tid, Whh, bhh, gxT, hsAll, flags, red);
}

// ---------------- launch ----------------

extern "C" void kernel_launch(void* const* d_in, const int* in_sizes, int n_in,
                              void* d_out, int out_size, void* d_ws, size_t ws_size,
                              hipStream_t stream)
{
  const float* features = (const float*)d_in[0];
  const float* Wp  = (const float*)d_in[1];
  const float* bp  = (const float*)d_in[2];
  const float* Wih = (const float*)d_in[3];
  const float* bih = (const float*)d_in[4];
  const float* Whh = (const float*)d_in[5];
  const float* bhh = (const float*)d_in[6];
  const float* W1  = (const float*)d_in[7];
  const float* b1  = (const float*)d_in[8];
  const float* W2  = (const float*)d_in[9];
  const float* b2  = (const float*)d_in[10];
  float* out = (float*)d_out;

  char* w = (char*)d_ws;
  auto alloc = [&](size_t bytes){ char* p = w; w += (bytes + 255) & ~(size_t)255; return p; };
  ushort* fb    = (ushort*)alloc((size_t)Mm*Dd*2);
  ushort* xb    = (ushort*)alloc((size_t)Mm*Hh*2);
  ushort* gxT   = (ushort*)alloc((size_t)Mm*3*Hh*2);
  ushort* hsAll = (ushort*)alloc((size_t)(Tt+1)*Bb*Hh*2);
  ushort* o1    = (ushort*)alloc((size_t)Mm*Hh*2);
  ushort* wpb   = (ushort*)alloc((size_t)Hh*Dd*2);
  ushort* wihb  = (ushort*)alloc((size_t)3*Hh*Hh*2);
  ushort* whhb  = (ushort*)alloc((size_t)3*Hh*Hh*2);
  ushort* w1b   = (ushort*)alloc((size_t)Hh*Hh*2);
  ushort* w2b   = (ushort*)alloc((size_t)1024*Hh*2);
  float*  b2p   = (float*)alloc(1024*4);
  int*    flags = (int*)alloc(256*4);
  int*    xccTab= (int*)alloc(264*4);
  ushort* hsT   = hsAll + (size_t)Bb*Hh;    // row (t*32+b) = h after step t

  // zero h(0) rows, flags, handshake tables (no giant sentinel fill anymore)
  hipMemsetAsync(hsAll, 0x00, (size_t)Bb*Hh*2, stream);
  hipMemsetAsync(flags, 0x00, 256*4, stream);
  hipMemsetAsync(xccTab, 0xFF, 264*4, stream);

  auto cvt = [&](const float* src, ushort* dst, size_t n){
    int n4 = (int)(n/4);
    hipLaunchKernelGGL(cvt_bf16, dim3((n4+255)/256), dim3(256), 0, stream, src, dst, n4);
  };
  cvt(features, fb, (size_t)Mm*Dd);
  cvt(Wp,  wpb,  (size_t)Hh*Dd);
  cvt(Wih, wihb, (size_t)3*Hh*Hh);
  cvt(Whh, whhb, (size_t)3*Hh*Hh);
  cvt(W1,  w1b,  (size_t)Hh*Hh);
  hipLaunchKernelGGL(pad_w2, dim3((1024*1024)/256), dim3(256), 0, stream, W2, b2, w2b, b2p);

  // x = relu(features @ Wp^T + bp)
  hipLaunchKernelGGL((gemm_bt<1,1,0,0>), dim3(Mm/128, Hh/128), dim3(256), 0, stream,
                     fb, wpb, bp, (void*)xb, Mm, Hh, Dd, Hh, Hh);
  // gxT[t][b][:] = x @ W_ih^T + b_ih   (row-permuted C write)
  hipLaunchKernelGGL((gemm_bt<0,1,0,1>), dim3(Mm/128, (3*Hh)/128), dim3(256), 0, stream,
                     xb, wihb, bih, (void*)gxT, Mm, 3*Hh, Hh, 3*Hh, 3*Hh);

  // GRU scan: 8 independent per-XCD batch groups, flag-published dataflow
  hipLaunchKernelGGL(gru_scan, dim3(256), dim3(512), 0, stream,
                     whhb, bhh, gxT, hsAll, flags, xccTab);

  // out1 = relu(hs @ W1^T + b1)  (row-permuted A read from hsT)
  hipLaunchKernelGGL((gemm_bt<1,1,1,0>), dim3(Mm/128, Hh/128), dim3(256), 0, stream,
                     hsT, w1b, b1, (void*)o1, Mm, Hh, Hh, Hh, Hh);
  // out = out1 @ W2p^T + b2p  (store only first 1000 cols, fp32)
  hipLaunchKernelGGL((gemm_bt<0,0,0,0>), dim3(Mm/128, 1024/128), dim3(256), 0, stream,
                     o1, w2b, b2p, (void*)out, Mm, 1024, Hh, Cc, Cc);
}

// Round 8
// 1889.869 us; speedup vs baseline: 2.1059x; 2.1059x over previous
//
#include <hip/hip_runtime.h>
#include <hip/hip_bf16.h>
#include <stdint.h>

#define Bb 32
#define Tt 512
#define Dd 1024
#define Hh 1024
#define Cc 1000
#define Mm (Bb*Tt)
#define SENT 0x7F7F7F7Fu

typedef float f32x4 __attribute__((ext_vector_type(4)));
typedef short bf16x8 __attribute__((ext_vector_type(8)));

#define MFMA16(a,b,c) __builtin_amdgcn_mfma_f32_16x16x32_bf16(a,b,c,0,0,0)

static __device__ __forceinline__ unsigned short f2b(float f){
  __hip_bfloat16 h = __float2bfloat16(f);
  union { __hip_bfloat16 h; unsigned short u; } cv; cv.h = h; return cv.u;
}
static __device__ __forceinline__ float b2f(unsigned short u){
  union { unsigned int i; float f; } cv; cv.i = ((unsigned int)u) << 16; return cv.f;
}

static __device__ __forceinline__ void async16(const ushort* g, ushort* l){
  __builtin_amdgcn_global_load_lds((const __attribute__((address_space(1))) unsigned int*)g,
                                   (__attribute__((address_space(3))) unsigned int*)l,
                                   16, 0, 0);
}

// h exchange:
//   FAST (same-XCD): agent scope = sc1 (bypass L1, coherent at XCD L2). R6-proven.
//   safe (cross-XCD): system scope = sc0 sc1 (coherent at L3). R4-proven.
template<int FAST>
static __device__ __forceinline__ bf16x8 h_load(const ushort* p){
  bf16x8 r;
  if constexpr (FAST)
    asm volatile("global_load_dwordx4 %0, %1, off sc1" : "=v"(r) : "v"(p) : "memory");
  else
    asm volatile("global_load_dwordx4 %0, %1, off sc0 sc1" : "=v"(r) : "v"(p) : "memory");
  return r;
}
template<int FAST>
static __device__ __forceinline__ void h_store(ushort* p, unsigned int v){
  if constexpr (FAST)
    asm volatile("global_store_dword %0, %1, off sc1" :: "v"(p), "v"(v) : "memory");
  else
    asm volatile("global_store_dword %0, %1, off sc0 sc1" :: "v"(p), "v"(v) : "memory");
}

static __device__ __forceinline__ int load4sys(const int* p){
  int v;
  asm volatile("global_load_dword %0, %1, off sc0 sc1" : "=v"(v) : "v"(p) : "memory");
  asm volatile("s_waitcnt vmcnt(0)" ::: "memory");
  return v;
}
static __device__ __forceinline__ void store4sys(int* p, int v){
  asm volatile("global_store_dword %0, %1, off sc0 sc1" :: "v"(p), "v"(v) : "memory");
}

// ---------------- conversion kernels ----------------

__global__ void cvt_bf16(const float* __restrict__ in, ushort* __restrict__ out, int n4){
  int i = blockIdx.x*256 + threadIdx.x;
  if (i < n4){
    const float4 v = ((const float4*)in)[i];
    ushort4 o;
    o.x = f2b(v.x); o.y = f2b(v.y); o.z = f2b(v.z); o.w = f2b(v.w);
    ((ushort4*)out)[i] = o;
  }
}

__global__ void pad_w2(const float* __restrict__ w2, const float* __restrict__ b2,
                       ushort* __restrict__ w2p, float* __restrict__ b2p){
  int i = blockIdx.x*256 + threadIdx.x;
  int r = i >> 10, c = i & 1023;
  w2p[i] = (r < Cc) ? f2b(w2[r*1024 + c]) : (ushort)0;
  if (i < 1024) b2p[i] = (i < Cc) ? b2[i] : 0.f;
}

// ---------------- generic bf16 MFMA GEMM (m97 structure) ----------------
// PERM_A / PERM_C: buffer stored row-permuted [(m&511)*32 + (m>>9)] = [t*32+b]

template<int RELU, int OUT_BF16, int PERM_A, int PERM_C>
__global__ __launch_bounds__(256) void gemm_bt(
    const ushort* __restrict__ A, const ushort* __restrict__ Bm,
    const float* __restrict__ bias, void* __restrict__ Cp,
    int M, int N, int K, int ldc, int nout)
{
  __shared__ ushort As[128*32];
  __shared__ ushort Bs[128*32];
  const int tid  = threadIdx.x;
  const int lane = tid & 63;
  const int wave = tid >> 6;
  const int wr = wave >> 1, wc = wave & 1;
  const int r0 = lane & 15, kg = lane >> 4;
  const int m0 = blockIdx.x*128, n0 = blockIdx.y*128;

  const int lrA0 = m0 + (tid>>2);
  const int lrA1 = lrA0 + 64;
  const size_t prA0 = PERM_A ? (size_t)((lrA0 & 511)*32 + (lrA0 >> 9)) : (size_t)lrA0;
  const size_t prA1 = PERM_A ? (size_t)((lrA1 & 511)*32 + (lrA1 >> 9)) : (size_t)lrA1;
  const ushort* aG0 = A  + prA0*K + (tid&3)*8;
  const ushort* aG1 = A  + prA1*K + (tid&3)*8;
  const ushort* bG  = Bm + (size_t)(n0 + (tid>>2))*K + (tid&3)*8;
  ushort* aL = As + tid*8;
  ushort* bL = Bs + tid*8;
  const size_t rstep = (size_t)64*K;

  f32x4 acc[4][4] = {};

  for (int kt = 0; kt < K; kt += 32){
    __syncthreads();
    async16(aG0 + kt, aL);
    async16(aG1 + kt, aL + 2048);
    async16(bG + kt,         bL);
    async16(bG + kt + rstep, bL + 2048);
    __syncthreads();
    bf16x8 af[4], bf_[4];
#pragma unroll
    for (int i=0;i<4;i++) af[i]  = *(const bf16x8*)&As[(wr*64 + i*16 + r0)*32 + kg*8];
#pragma unroll
    for (int j=0;j<4;j++) bf_[j] = *(const bf16x8*)&Bs[(wc*64 + j*16 + r0)*32 + kg*8];
#pragma unroll
    for (int i=0;i<4;i++)
#pragma unroll
      for (int j=0;j<4;j++)
        acc[i][j] = MFMA16(af[i], bf_[j], acc[i][j]);
  }

  const int rowb = m0 + wr*64 + kg*4;
  const int colb = n0 + wc*64 + r0;
#pragma unroll
  for (int i=0;i<4;i++){
#pragma unroll
    for (int j=0;j<4;j++){
      const int c = colb + j*16;
      if (c >= nout) continue;
      const float bv = bias ? bias[c] : 0.f;
#pragma unroll
      for (int q=0;q<4;q++){
        const int r = rowb + i*16 + q;
        const size_t pr = PERM_C ? (size_t)((r & 511)*32 + (r >> 9)) : (size_t)r;
        float v = acc[i][j][q] + bv;
        if (RELU) v = fmaxf(v, 0.f);
        if (OUT_BF16) ((ushort*)Cp)[pr*ldc + c] = f2b(v);
        else          ((float* )Cp)[pr*ldc + c] = v;
      }
    }
  }
}

// ---------------- persistent GRU scan, batch-partitioned per XCD ----------------
// 256 WGs of 512 thr. Group g = {bid : bid%8==g} (32 members) owns batches
// [4g,4g+4); member m owns hidden units [32m,32m+32). Exchange = sentinel
// write-once rows of hsAll (the poll IS the data load — one L2 hop).
// gx(t+1) register-double-buffered; single __syncthreads/step via red dbuf.

template<int FAST>
static __device__ __forceinline__ void scan_body(
    const int g, const int m, const int tid,
    const ushort* __restrict__ Whh, const float* __restrict__ bhh,
    const ushort* __restrict__ gxT, ushort* __restrict__ hsAll,
    float* __restrict__ red)
{
  const int wave = tid >> 6;          // K-slice [wave*128, +128)
  const int lane = tid & 63;
  const int r0 = lane & 15, kg = lane >> 4;
  const int kbase = wave*128 + kg*8;

  // weight-stationary: 24 bf16x8 frags (96 VGPR), rows [gate*1024 + m*32 + ...]
  bf16x8 wb[6][4];
#pragma unroll
  for (int n=0;n<6;n++){
    const ushort* wr_ = Whh + ((size_t)((n>>1)*1024 + m*32 + (n&1)*16 + r0))*1024 + kbase;
#pragma unroll
    for (int ks=0;ks<4;ks++)
      wb[n][ks] = *(const bf16x8*)(wr_ + ks*32);
  }

  // epilogue role: threads 0..63, batch eb, unit pair (u0, u0+1)
  const int eb = tid >> 4;
  const int u0 = (tid & 15)*2;
  const int jg = m*32 + u0;
  float br0=0,br1=0,bz0=0,bz1=0,bn0=0,bn1=0;
  if (tid < 64){
    br0 = bhh[jg];       br1 = bhh[jg+1];
    bz0 = bhh[1024+jg];  bz1 = bhh[1024+jg+1];
    bn0 = bhh[2048+jg];  bn1 = bhh[2048+jg+1];
  }
  float hold0 = 0.f, hold1 = 0.f;

  // gx register double-buffer (wave0 only): gx(0) issued now, drained by first poll
  unsigned xr=0, xz=0, xn=0, xrN=0, xzN=0, xnN=0;
  if (tid < 64){
    const ushort* gb = gxT + (size_t)(g*4 + eb)*3072 + jg;
    asm volatile("global_load_dword %0, %1, off" : "=v"(xr) : "v"(gb));
    asm volatile("global_load_dword %0, %1, off" : "=v"(xz) : "v"(gb + 1024));
    asm volatile("global_load_dword %0, %1, off" : "=v"(xn) : "v"(gb + 2048));
  }

  for (int t = 0; t < Tt; ++t){
    const int buf = t & 1;

    // pin weights in regs (prevent per-step rematerialization from L2)
#pragma unroll
    for (int n=0;n<6;n++)
#pragma unroll
      for (int ks=0;ks<4;ks++)
        asm volatile("" : "+v"(wb[n][ks]));

    // ---- poll-load h(t): this group's 4 batch rows (lanes r0>=4 duplicate r0&3).
    // The poll IS the data load: when it passes, ha[] is ready for MFMA.
    const ushort* aB = hsAll + (size_t)(t*32 + g*4 + (r0 & 3))*1024 + kbase;
    bf16x8 ha[4];
    int again;
    do {
#pragma unroll
      for (int ks=0;ks<4;ks++) ha[ks] = h_load<FAST>(aB + ks*32);
      asm volatile("s_waitcnt vmcnt(0)" ::: "memory");
      __builtin_amdgcn_sched_barrier(0);
      unsigned sent = 0;
#pragma unroll
      for (int ks=0;ks<4;ks++){
        union { bf16x8 v; unsigned u[4]; } A; A.v = ha[ks];
#pragma unroll
        for (int q=0;q<4;q++) sent |= (A.u[q] == SENT);
      }
      again = __any((int)sent);
    } while (again);

    // ---- gx(t+1) prefetch AFTER the poll: HBM latency hides under
    // MFMA+reduce+epilogue+next-poll; gx(t) is consumed from registers below.
    if (tid < 64 && t+1 < Tt){
      const ushort* gb = gxT + (size_t)((t+1)*32 + g*4 + eb)*3072 + jg;
      asm volatile("global_load_dword %0, %1, off" : "=v"(xrN) : "v"(gb));
      asm volatile("global_load_dword %0, %1, off" : "=v"(xzN) : "v"(gb + 1024));
      asm volatile("global_load_dword %0, %1, off" : "=v"(xnN) : "v"(gb + 2048));
    }

    f32x4 acc[6] = {};
#pragma unroll
    for (int ks=0;ks<4;ks++)
#pragma unroll
      for (int n=0;n<6;n++)
        acc[n] = MFMA16(ha[ks], wb[n][ks], acc[n]);

#pragma unroll
    for (int n=0;n<6;n++)
      *(f32x4*)&red[buf*12288 + (wave*6 + n)*256 + lane*4] = acc[n];
    __syncthreads();   // single barrier per step (red double-buffered)

    if (tid < 64){
      float rs0=0,zs0=0,ns0=0, rs1=0,zs1=0,ns1=0;
      const float* rb = red + buf*12288;
#pragma unroll
      for (int w=0;w<8;w++){
        int j;
        j = u0;      rs0 += rb[(w*6 + (j>>4))*256 + (j&15)*4 + eb];
        j = u0+1;    rs1 += rb[(w*6 + (j>>4))*256 + (j&15)*4 + eb];
        j = 32+u0;   zs0 += rb[(w*6 + (j>>4))*256 + (j&15)*4 + eb];
        j = 33+u0;   zs1 += rb[(w*6 + (j>>4))*256 + (j&15)*4 + eb];
        j = 64+u0;   ns0 += rb[(w*6 + (j>>4))*256 + (j&15)*4 + eb];
        j = 65+u0;   ns1 += rb[(w*6 + (j>>4))*256 + (j&15)*4 + eb];
      }
      float h0, h1;
      {
        const float r = 1.f/(1.f + __expf(-(b2f((ushort)(xr & 0xffff)) + rs0 + br0)));
        const float z = 1.f/(1.f + __expf(-(b2f((ushort)(xz & 0xffff)) + zs0 + bz0)));
        const float a = b2f((ushort)(xn & 0xffff)) + r*(ns0 + bn0);
        const float e = __expf(-2.f*a);
        const float n = (1.f - e)/(1.f + e);
        h0 = (1.f - z)*n + z*hold0; hold0 = h0;
      }
      {
        const float r = 1.f/(1.f + __expf(-(b2f((ushort)(xr >> 16)) + rs1 + br1)));
        const float z = 1.f/(1.f + __expf(-(b2f((ushort)(xz >> 16)) + zs1 + bz1)));
        const float a = b2f((ushort)(xn >> 16)) + r*(ns1 + bn1);
        const float e = __expf(-2.f*a);
        const float n = (1.f - e)/(1.f + e);
        h1 = (1.f - z)*n + z*hold1; hold1 = h1;
      }
      const unsigned packed = (unsigned)f2b(h0) | ((unsigned)f2b(h1) << 16);
      // single store = data + publish (write-once, dword-atomic, sentinel-tagged)
      h_store<FAST>(hsAll + (size_t)((t+1)*32 + g*4 + eb)*1024 + jg, packed);
      xr = xrN; xz = xzN; xn = xnN;
    }
  }
}

__global__ __launch_bounds__(512, 1) void gru_scan(
    const ushort* __restrict__ Whh, const float* __restrict__ bhh,
    const ushort* __restrict__ gxT,   // [t][b][3H]
    ushort* __restrict__ hsAll,       // [Tt+1][32][1024]; rows 0..31 zeroed, rest SENT
    int* __restrict__ xccTab)         // [0..255]=XCC publish, [256..263]=decision; init -1
{
  __shared__ float red[2*12288];
  __shared__ int fastFlag;
  const int bid = blockIdx.x;
  const int g = bid & 7, m = bid >> 3;
  const int tid = threadIdx.x;
  int* decTab = xccTab + 256;

  // mode agreement (R6-proven): publish XCC_ID; member 0 decides; bounded spin
  if (tid == 0){
    int myxcc;
    asm volatile("s_getreg_b32 %0, hwreg(HW_REG_XCC_ID)" : "=s"(myxcc));
    store4sys(&xccTab[bid], myxcc);
    if (m == 0){
      int ok = 1;
      long budget = 200000;
      for (int p = 0; p < 32 && ok; ++p){
        int v;
        do {
          v = load4sys(&xccTab[p*8 + g]);
          if (v == -1){ __builtin_amdgcn_s_sleep(1); if (--budget <= 0){ ok = 0; break; } }
        } while (v == -1);
        if (v != myxcc) ok = 0;
      }
      store4sys(&decTab[g], ok);
      fastFlag = ok;
    } else {
      int v;
      do {
        v = load4sys(&decTab[g]);
        if (v == -1) __builtin_amdgcn_s_sleep(1);
      } while (v == -1);
      fastFlag = v;
    }
  }
  __syncthreads();

  if (fastFlag) scan_body<1>(g, m, tid, Whh, bhh, gxT, hsAll, red);
  else          scan_body<0>(g, m, tid, Whh, bhh, gxT, hsAll, red);
}

// ---------------- launch ----------------

extern "C" void kernel_launch(void* const* d_in, const int* in_sizes, int n_in,
                              void* d_out, int out_size, void* d_ws, size_t ws_size,
                              hipStream_t stream)
{
  const float* features = (const float*)d_in[0];
  const float* Wp  = (const float*)d_in[1];
  const float* bp  = (const float*)d_in[2];
  const float* Wih = (const float*)d_in[3];
  const float* bih = (const float*)d_in[4];
  const float* Whh = (const float*)d_in[5];
  const float* bhh = (const float*)d_in[6];
  const float* W1  = (const float*)d_in[7];
  const float* b1  = (const float*)d_in[8];
  const float* W2  = (const float*)d_in[9];
  const float* b2  = (const float*)d_in[10];
  float* out = (float*)d_out;

  char* w = (char*)d_ws;
  auto alloc = [&](size_t bytes){ char* p = w; w += (bytes + 255) & ~(size_t)255; return p; };
  ushort* fb    = (ushort*)alloc((size_t)Mm*Dd*2);
  ushort* xb    = (ushort*)alloc((size_t)Mm*Hh*2);
  ushort* gxT   = (ushort*)alloc((size_t)Mm*3*Hh*2);
  ushort* hsAll = (ushort*)alloc((size_t)(Tt+1)*Bb*Hh*2);
  ushort* o1    = (ushort*)alloc((size_t)Mm*Hh*2);
  ushort* wpb   = (ushort*)alloc((size_t)Hh*Dd*2);
  ushort* wihb  = (ushort*)alloc((size_t)3*Hh*Hh*2);
  ushort* whhb  = (ushort*)alloc((size_t)3*Hh*Hh*2);
  ushort* w1b   = (ushort*)alloc((size_t)Hh*Hh*2);
  ushort* w2b   = (ushort*)alloc((size_t)1024*Hh*2);
  float*  b2p   = (float*)alloc(1024*4);
  int*    xccTab= (int*)alloc(264*4);
  ushort* hsT   = hsAll + (size_t)Bb*Hh;    // row (t*32+b) = h after step t

  // sentinel-fill h exchange buffer, zero the h(0) rows, reset handshake tables
  hipMemsetAsync(hsAll, 0x7F, (size_t)(Tt+1)*Bb*Hh*2, stream);
  hipMemsetAsync(hsAll, 0x00, (size_t)Bb*Hh*2, stream);
  hipMemsetAsync(xccTab, 0xFF, 264*4, stream);

  auto cvt = [&](const float* src, ushort* dst, size_t n){
    int n4 = (int)(n/4);
    hipLaunchKernelGGL(cvt_bf16, dim3((n4+255)/256), dim3(256), 0, stream, src, dst, n4);
  };
  cvt(features, fb, (size_t)Mm*Dd);
  cvt(Wp,  wpb,  (size_t)Hh*Dd);
  cvt(Wih, wihb, (size_t)3*Hh*Hh);
  cvt(Whh, whhb, (size_t)3*Hh*Hh);
  cvt(W1,  w1b,  (size_t)Hh*Hh);
  hipLaunchKernelGGL(pad_w2, dim3((1024*1024)/256), dim3(256), 0, stream, W2, b2, w2b, b2p);

  // x = relu(features @ Wp^T + bp)
  hipLaunchKernelGGL((gemm_bt<1,1,0,0>), dim3(Mm/128, Hh/128), dim3(256), 0, stream,
                     fb, wpb, bp, (void*)xb, Mm, Hh, Dd, Hh, Hh);
  // gxT[t][b][:] = x @ W_ih^T + b_ih   (row-permuted C write)
  hipLaunchKernelGGL((gemm_bt<0,1,0,1>), dim3(Mm/128, (3*Hh)/128), dim3(256), 0, stream,
                     xb, wihb, bih, (void*)gxT, Mm, 3*Hh, Hh, 3*Hh, 3*Hh);

  // GRU scan: 8 independent per-XCD batch groups, sentinel dataflow
  hipLaunchKernelGGL(gru_scan, dim3(256), dim3(512), 0, stream,
                     whhb, bhh, gxT, hsAll, xccTab);

  // out1 = relu(hs @ W1^T + b1)  (row-permuted A read from hsT)
  hipLaunchKernelGGL((gemm_bt<1,1,1,0>), dim3(Mm/128, Hh/128), dim3(256), 0, stream,
                     hsT, w1b, b1, (void*)o1, Mm, Hh, Hh, Hh, Hh);
  // out = out1 @ W2p^T + b2p  (store only first 1000 cols, fp32)
  hipLaunchKernelGGL((gemm_bt<0,0,0,0>), dim3(Mm/128, 1024/128), dim3(256), 0, stream,
                     o1, w2b, b2p, (void*)out, Mm, 1024, Hh, Cc, Cc);
}